// Round 1
// baseline (330.321 us; speedup 1.0000x reference)
//
#include <hip/hip_runtime.h>
#include <stdint.h>

#define EMB_DIM 192      // 3 coords * 32 freqs * 2 (sin,cos)
#define KIN 384
#define CDIM 32
#define TDIM 4
#define N_Y 50000
#define N_X 32768
#define KNBR 8
#define ECNT (N_X*KNBR)  // 262144

typedef __attribute__((ext_vector_type(8))) short bf16x8;
typedef __attribute__((ext_vector_type(4))) float f32x4;

static __device__ __forceinline__ short f2bf(float f){
  unsigned u = __float_as_uint(f);
  u = u + 0x7FFFu + ((u >> 16) & 1u);   // RNE
  return (short)(u >> 16);
}
static __device__ __forceinline__ float geluf(float x){
  // jax.nn.gelu default (approximate=True, tanh form); 0.5*(1+tanh(t)) = sigmoid(2t)
  float t = 0.7978845608028654f * x * (1.0f + 0.044715f * x * x);
  return x / (1.0f + __expf(-2.0f * t));
}

// ---- embeddings: out row = [sin(p_d*f_i), cos(p_d*f_i)] at d*64 + 2*i ----
__global__ __launch_bounds__(256) void embed_kernel(const float* __restrict__ pts,
                                                    short* __restrict__ emb, int n){
  int id = blockIdx.x * 256 + threadIdx.x;
  int total = n * 96;                       // 3 coords * 32 freqs
  if (id >= total) return;
  int row = id / 96;
  int q = id - row * 96;
  int d = q >> 5, i = q & 31;
  float p = pts[row * 3 + d];
  float f = __expf(-9.210340371976184f * (float)i * (1.0f / 32.0f)); // (1e-4)^(i/32)
  float s, c;
  __sincosf(p * f, &s, &c);
  unsigned pack = (unsigned)(unsigned short)f2bf(s) |
                  ((unsigned)(unsigned short)f2bf(c) << 16);
  *(unsigned*)&emb[(size_t)row * EMB_DIM + d * 64 + 2 * i] = pack;
}

// ---- W (K,N) fp32 -> W^T (N,K) bf16 so MFMA B-frag loads are contiguous in K ----
__global__ __launch_bounds__(256) void transpose_cast(const float* __restrict__ src,
                                                      short* __restrict__ dst, int K, int N){
  int id = blockIdx.x * 256 + threadIdx.x;
  if (id >= K * N) return;
  int n = id / K, k = id - n * K;
  dst[n * K + k] = f2bf(src[k * N + n]);
}

// ---- fused 4-layer MLP over a 64-edge M-tile, activations chained in LDS ----
__global__ __launch_bounds__(256, 2) void fused_mlp(
    const short* __restrict__ yemb, const short* __restrict__ xemb,
    const int* __restrict__ nidx,
    const short* __restrict__ w0t, const float* __restrict__ b0,
    const short* __restrict__ w1t, const float* __restrict__ b1,
    const short* __restrict__ w2t, const float* __restrict__ b2,
    const short* __restrict__ w3t, const float* __restrict__ b3,
    float* __restrict__ kern)
{
  __shared__ int s_idx[64];
  __shared__ __attribute__((aligned(16))) short s_a[2][64 * 40];   // layer0 K-chunk stage (pad 32->40)
  __shared__ __attribute__((aligned(16))) short s_h1[64 * 136];    // h1 (128 cols, pad->136); reused as h3
  __shared__ __attribute__((aligned(16))) short s_h2[64 * 264];    // h2 (256 cols, pad->264)

  const int tid  = threadIdx.x;
  const int e0   = blockIdx.x * 64;
  if (tid < 64) s_idx[tid] = nidx[e0 + tid];
  const int wave = tid >> 6, lane = tid & 63;
  const int quad = lane >> 4, l15 = lane & 15;
  const int r    = tid >> 2, seg = tid & 3;  // staging: row, 8-elem segment
  __syncthreads();

  const short* ybase = yemb + (size_t)s_idx[r] * EMB_DIM + seg * 8;
  const short* xbase = xemb + (size_t)((e0 + r) >> 3) * EMB_DIM + seg * 8;

  // ---------- layer 0: 384 -> 128, GELU ----------
  f32x4 acc0[4][2];
  #pragma unroll
  for (int mt = 0; mt < 4; ++mt)
    #pragma unroll
    for (int nt = 0; nt < 2; ++nt) acc0[mt][nt] = (f32x4){0.f, 0.f, 0.f, 0.f};

  for (int ch = 0; ch < 12; ++ch) {
    const short* src = (ch < 6) ? (ybase + ch * 32) : (xbase + (ch - 6) * 32);
    *(uint4*)&s_a[ch & 1][r * 40 + seg * 8] = *(const uint4*)src;
    __syncthreads();
    bf16x8 a[4], b[2];
    #pragma unroll
    for (int mt = 0; mt < 4; ++mt)
      a[mt] = *(const bf16x8*)&s_a[ch & 1][(mt * 16 + l15) * 40 + quad * 8];
    #pragma unroll
    for (int nt = 0; nt < 2; ++nt)
      b[nt] = *(const bf16x8*)&w0t[(size_t)(wave * 32 + nt * 16 + l15) * 384 + ch * 32 + quad * 8];
    #pragma unroll
    for (int mt = 0; mt < 4; ++mt)
      #pragma unroll
      for (int nt = 0; nt < 2; ++nt)
        acc0[mt][nt] = __builtin_amdgcn_mfma_f32_16x16x32_bf16(a[mt], b[nt], acc0[mt][nt], 0, 0, 0);
  }
  #pragma unroll
  for (int nt = 0; nt < 2; ++nt) {
    int col = wave * 32 + nt * 16 + l15;
    float bias = b0[col];
    #pragma unroll
    for (int mt = 0; mt < 4; ++mt)
      #pragma unroll
      for (int rg = 0; rg < 4; ++rg) {
        int row = mt * 16 + quad * 4 + rg;
        s_h1[row * 136 + col] = f2bf(geluf(acc0[mt][nt][rg] + bias));
      }
  }
  __syncthreads();

  // ---------- layer 1: 128 -> 256, GELU ----------
  f32x4 acc1[4][4];
  #pragma unroll
  for (int mt = 0; mt < 4; ++mt)
    #pragma unroll
    for (int nt = 0; nt < 4; ++nt) acc1[mt][nt] = (f32x4){0.f, 0.f, 0.f, 0.f};
  for (int ch = 0; ch < 4; ++ch) {
    bf16x8 a[4], b[4];
    #pragma unroll
    for (int mt = 0; mt < 4; ++mt)
      a[mt] = *(const bf16x8*)&s_h1[(mt * 16 + l15) * 136 + ch * 32 + quad * 8];
    #pragma unroll
    for (int nt = 0; nt < 4; ++nt)
      b[nt] = *(const bf16x8*)&w1t[(size_t)(wave * 64 + nt * 16 + l15) * 128 + ch * 32 + quad * 8];
    #pragma unroll
    for (int mt = 0; mt < 4; ++mt)
      #pragma unroll
      for (int nt = 0; nt < 4; ++nt)
        acc1[mt][nt] = __builtin_amdgcn_mfma_f32_16x16x32_bf16(a[mt], b[nt], acc1[mt][nt], 0, 0, 0);
  }
  #pragma unroll
  for (int nt = 0; nt < 4; ++nt) {
    int col = wave * 64 + nt * 16 + l15;
    float bias = b1[col];
    #pragma unroll
    for (int mt = 0; mt < 4; ++mt)
      #pragma unroll
      for (int rg = 0; rg < 4; ++rg) {
        int row = mt * 16 + quad * 4 + rg;
        s_h2[row * 264 + col] = f2bf(geluf(acc1[mt][nt][rg] + bias));
      }
  }
  __syncthreads();

  // ---------- layer 2: 256 -> 128, GELU ----------
  f32x4 acc2[4][2];
  #pragma unroll
  for (int mt = 0; mt < 4; ++mt)
    #pragma unroll
    for (int nt = 0; nt < 2; ++nt) acc2[mt][nt] = (f32x4){0.f, 0.f, 0.f, 0.f};
  for (int ch = 0; ch < 8; ++ch) {
    bf16x8 a[4], b[2];
    #pragma unroll
    for (int mt = 0; mt < 4; ++mt)
      a[mt] = *(const bf16x8*)&s_h2[(mt * 16 + l15) * 264 + ch * 32 + quad * 8];
    #pragma unroll
    for (int nt = 0; nt < 2; ++nt)
      b[nt] = *(const bf16x8*)&w2t[(size_t)(wave * 32 + nt * 16 + l15) * 256 + ch * 32 + quad * 8];
    #pragma unroll
    for (int mt = 0; mt < 4; ++mt)
      #pragma unroll
      for (int nt = 0; nt < 2; ++nt)
        acc2[mt][nt] = __builtin_amdgcn_mfma_f32_16x16x32_bf16(a[mt], b[nt], acc2[mt][nt], 0, 0, 0);
  }
  // write h3 into s_h1 (safe: last s_h1 reads were layer 1, fenced by sync after epi-1)
  #pragma unroll
  for (int nt = 0; nt < 2; ++nt) {
    int col = wave * 32 + nt * 16 + l15;
    float bias = b2[col];
    #pragma unroll
    for (int mt = 0; mt < 4; ++mt)
      #pragma unroll
      for (int rg = 0; rg < 4; ++rg) {
        int row = mt * 16 + quad * 4 + rg;
        s_h1[row * 136 + col] = f2bf(geluf(acc2[mt][nt][rg] + bias));
      }
  }
  __syncthreads();

  // ---------- layer 3: 128 -> 32, linear ----------
  f32x4 acc3[2];
  acc3[0] = (f32x4){0.f, 0.f, 0.f, 0.f};
  acc3[1] = (f32x4){0.f, 0.f, 0.f, 0.f};
  for (int ch = 0; ch < 4; ++ch) {
    bf16x8 a3 = *(const bf16x8*)&s_h1[(wave * 16 + l15) * 136 + ch * 32 + quad * 8];
    bf16x8 b3f[2];
    #pragma unroll
    for (int nt = 0; nt < 2; ++nt)
      b3f[nt] = *(const bf16x8*)&w3t[(size_t)(nt * 16 + l15) * 128 + ch * 32 + quad * 8];
    #pragma unroll
    for (int nt = 0; nt < 2; ++nt)
      acc3[nt] = __builtin_amdgcn_mfma_f32_16x16x32_bf16(a3, b3f[nt], acc3[nt], 0, 0, 0);
  }
  #pragma unroll
  for (int nt = 0; nt < 2; ++nt) {
    int col = nt * 16 + l15;
    float bias = b3[col];
    #pragma unroll
    for (int rg = 0; rg < 4; ++rg) {
      int row = wave * 16 + quad * 4 + rg;
      kern[(size_t)(e0 + row) * CDIM + col] = acc3[nt][rg] + bias;
    }
  }
}

// ---- out[t][x][c] = sum_j kern[x*8+j][c] * f_y[t][idx[x*8+j]][c] ----
__global__ __launch_bounds__(256) void reduce_out(
    const float* __restrict__ kern, const float* __restrict__ f_y,
    const int* __restrict__ nidx, float* __restrict__ out)
{
  int id = blockIdx.x * 256 + threadIdx.x;
  if (id >= N_X * CDIM) return;
  int x = id >> 5, c = id & 31;
  float acc[TDIM] = {0.f, 0.f, 0.f, 0.f};
  int base = x * KNBR;
  #pragma unroll
  for (int j = 0; j < KNBR; ++j) {
    int idx = nidx[base + j];
    float kv = kern[(size_t)(base + j) * CDIM + c];
    #pragma unroll
    for (int t = 0; t < TDIM; ++t)
      acc[t] += kv * f_y[((size_t)t * N_Y + idx) * CDIM + c];
  }
  #pragma unroll
  for (int t = 0; t < TDIM; ++t)
    out[((size_t)t * N_X + x) * CDIM + c] = acc[t];
}

extern "C" void kernel_launch(void* const* d_in, const int* in_sizes, int n_in,
                              void* d_out, int out_size, void* d_ws, size_t ws_size,
                              hipStream_t stream)
{
  const float* y   = (const float*)d_in[0];
  const float* x   = (const float*)d_in[1];
  const float* f_y = (const float*)d_in[2];
  const int*  nidx = (const int*)d_in[3];
  const float* W0 = (const float*)d_in[4];  const float* b0 = (const float*)d_in[5];
  const float* W1 = (const float*)d_in[6];  const float* b1 = (const float*)d_in[7];
  const float* W2 = (const float*)d_in[8];  const float* b2 = (const float*)d_in[9];
  const float* W3 = (const float*)d_in[10]; const float* b3 = (const float*)d_in[11];

  char* ws = (char*)d_ws;
  short* yemb = (short*)(ws + 0);          // 50000*192*2 = 19,200,000
  short* xemb = (short*)(ws + 19200000);   // 32768*192*2 = 12,582,912
  short* w0t  = (short*)(ws + 31782912);   // 128*384*2  =     98,304
  short* w1t  = (short*)(ws + 31881216);   // 256*128*2  =     65,536
  short* w2t  = (short*)(ws + 31946752);   // 128*256*2  =     65,536
  short* w3t  = (short*)(ws + 32012288);   //  32*128*2  =      8,192
  float* kern = (float*)(ws + 32020480);   // 262144*32*4 = 33,554,432 (total ~65.6 MB)

  hipLaunchKernelGGL(embed_kernel, dim3((N_Y * 96 + 255) / 256), dim3(256), 0, stream, y, yemb, N_Y);
  hipLaunchKernelGGL(embed_kernel, dim3((N_X * 96 + 255) / 256), dim3(256), 0, stream, x, xemb, N_X);
  hipLaunchKernelGGL(transpose_cast, dim3((384 * 128 + 255) / 256), dim3(256), 0, stream, W0, w0t, 384, 128);
  hipLaunchKernelGGL(transpose_cast, dim3((128 * 256 + 255) / 256), dim3(256), 0, stream, W1, w1t, 128, 256);
  hipLaunchKernelGGL(transpose_cast, dim3((256 * 128 + 255) / 256), dim3(256), 0, stream, W2, w2t, 256, 128);
  hipLaunchKernelGGL(transpose_cast, dim3((128 * 32 + 255) / 256), dim3(256), 0, stream, W3, w3t, 128, 32);
  hipLaunchKernelGGL(fused_mlp, dim3(ECNT / 64), dim3(256), 0, stream,
                     yemb, xemb, nidx, w0t, b0, w1t, b1, w2t, b2, w3t, b3, kern);
  hipLaunchKernelGGL(reduce_out, dim3((N_X * CDIM + 255) / 256), dim3(256), 0, stream,
                     kern, f_y, nidx, (float*)d_out);
}

// Round 2
// 320.815 us; speedup vs baseline: 1.0296x; 1.0296x over previous
//
#include <hip/hip_runtime.h>
#include <stdint.h>

#define EMB_DIM 192      // 3 coords * 32 freqs * 2 (sin,cos)
#define KIN 384
#define CDIM 32
#define TDIM 4
#define N_Y 50000
#define N_X 32768
#define KNBR 8
#define ECNT (N_X*KNBR)  // 262144

typedef __attribute__((ext_vector_type(8))) short bf16x8;
typedef __attribute__((ext_vector_type(4))) float f32x4;

static __device__ __forceinline__ short f2bf(float f){
  unsigned u = __float_as_uint(f);
  u = u + 0x7FFFu + ((u >> 16) & 1u);   // RNE
  return (short)(u >> 16);
}
static __device__ __forceinline__ float geluf(float x){
  // jax.nn.gelu (approximate tanh form); 0.5*(1+tanh(t)) = sigmoid(2t)
  float t = 0.7978845608028654f * x * (1.0f + 0.044715f * x * x);
  return x / (1.0f + __expf(-2.0f * t));
}

// ---- embeddings for y (rows 0..N_Y-1) and x (rows N_Y..): one launch ----
__global__ __launch_bounds__(256) void embed_all(const float* __restrict__ ypts,
                                                 const float* __restrict__ xpts,
                                                 short* __restrict__ emb){
  int id = blockIdx.x * 256 + threadIdx.x;
  int total = (N_Y + N_X) * 96;             // rows * (3 coords * 32 freqs)
  if (id >= total) return;
  int row = id / 96;
  int q = id - row * 96;
  int d = q >> 5, i = q & 31;
  float p = (row < N_Y) ? ypts[row * 3 + d] : xpts[(row - N_Y) * 3 + d];
  float f = __expf(-9.210340371976184f * (float)i * (1.0f / 32.0f)); // (1e-4)^(i/32)
  float s, c;
  __sincosf(p * f, &s, &c);
  unsigned pack = (unsigned)(unsigned short)f2bf(s) |
                  ((unsigned)(unsigned short)f2bf(c) << 16);
  *(unsigned*)&emb[(size_t)row * EMB_DIM + d * 64 + 2 * i] = pack;
}

// ---- all four W (K,N) fp32 -> W^T (N,K) bf16 in one launch ----
__global__ __launch_bounds__(256) void transpose_all(
    const float* __restrict__ W0, const float* __restrict__ W1,
    const float* __restrict__ W2, const float* __restrict__ W3,
    short* __restrict__ w0t, short* __restrict__ w1t,
    short* __restrict__ w2t, short* __restrict__ w3t){
  int id = blockIdx.x * 256 + threadIdx.x;
  const float* src; short* dst; int K, N, loc;
  if      (id < 49152)  { src = W0; dst = w0t; K = 384; N = 128; loc = id; }
  else if (id < 81920)  { src = W1; dst = w1t; K = 128; N = 256; loc = id - 49152; }
  else if (id < 114688) { src = W2; dst = w2t; K = 256; N = 128; loc = id - 81920; }
  else if (id < 118784) { src = W3; dst = w3t; K = 128; N = 32;  loc = id - 114688; }
  else return;
  int n = loc / K, k = loc - n * K;
  dst[n * K + k] = f2bf(src[k * N + n]);
}

// ---- fused: gather-MLP (4 layers, MFMA) + K=8 segment reduce, per 64-edge block ----
__global__ __launch_bounds__(256, 3) void fused_mlp(
    const short* __restrict__ yemb, const short* __restrict__ xemb,
    const int* __restrict__ nidx, const float* __restrict__ f_y,
    const short* __restrict__ w0t, const float* __restrict__ b0,
    const short* __restrict__ w1t, const float* __restrict__ b1,
    const short* __restrict__ w2t, const float* __restrict__ b2,
    const short* __restrict__ w3t, const float* __restrict__ b3,
    float* __restrict__ out)
{
  // LDS carve: idx[64] | h1 (64x136 bf16) | h2 (64x264 bf16, aliased by kern 64x33 f32)
  __shared__ __attribute__((aligned(16))) char smem[256 + 17408 + 33792];
  int*   s_idx  = (int*)smem;
  short* s_h1   = (short*)(smem + 256);
  short* s_h2   = (short*)(smem + 256 + 17408);
  float* s_kern = (float*)(smem + 256 + 17408);   // alias of s_h2 (safe: see syncs)

  const int tid  = threadIdx.x;
  const int e0   = blockIdx.x * 64;
  if (tid < 64) s_idx[tid] = nidx[e0 + tid];
  const int wave = tid >> 6, lane = tid & 63;
  const int quad = lane >> 4, l15 = lane & 15;
  __syncthreads();

  // per-mt gathered row base pointers (A-frag rows m = mt*16 + l15)
  const short* yrow[4];
  const short* xrow[4];
  #pragma unroll
  for (int mt = 0; mt < 4; ++mt) {
    int m = mt * 16 + l15;
    yrow[mt] = yemb + (size_t)s_idx[m] * EMB_DIM + quad * 8;
    xrow[mt] = xemb + (size_t)((e0 + m) >> 3) * EMB_DIM + quad * 8;
  }

  // ---------- layer 0: 384 -> 128, GELU (A-frags direct from global) ----------
  f32x4 acc0[4][2];
  #pragma unroll
  for (int mt = 0; mt < 4; ++mt)
    #pragma unroll
    for (int nt = 0; nt < 2; ++nt) acc0[mt][nt] = (f32x4){0.f, 0.f, 0.f, 0.f};

  #pragma unroll 2
  for (int ch = 0; ch < 12; ++ch) {
    bf16x8 a[4], b[2];
    #pragma unroll
    for (int mt = 0; mt < 4; ++mt) {
      const short* base = (ch < 6) ? (yrow[mt] + ch * 32) : (xrow[mt] + (ch - 6) * 32);
      a[mt] = *(const bf16x8*)base;
    }
    #pragma unroll
    for (int nt = 0; nt < 2; ++nt)
      b[nt] = *(const bf16x8*)&w0t[(size_t)(wave * 32 + nt * 16 + l15) * 384 + ch * 32 + quad * 8];
    #pragma unroll
    for (int mt = 0; mt < 4; ++mt)
      #pragma unroll
      for (int nt = 0; nt < 2; ++nt)
        acc0[mt][nt] = __builtin_amdgcn_mfma_f32_16x16x32_bf16(a[mt], b[nt], acc0[mt][nt], 0, 0, 0);
  }
  #pragma unroll
  for (int nt = 0; nt < 2; ++nt) {
    int col = wave * 32 + nt * 16 + l15;
    float bias = b0[col];
    #pragma unroll
    for (int mt = 0; mt < 4; ++mt)
      #pragma unroll
      for (int rg = 0; rg < 4; ++rg) {
        int row = mt * 16 + quad * 4 + rg;
        s_h1[row * 136 + col] = f2bf(geluf(acc0[mt][nt][rg] + bias));
      }
  }
  __syncthreads();

  // ---------- layer 1: 128 -> 256, GELU ----------
  f32x4 acc1[4][4];
  #pragma unroll
  for (int mt = 0; mt < 4; ++mt)
    #pragma unroll
    for (int nt = 0; nt < 4; ++nt) acc1[mt][nt] = (f32x4){0.f, 0.f, 0.f, 0.f};
  for (int ch = 0; ch < 4; ++ch) {
    bf16x8 a[4], b[4];
    #pragma unroll
    for (int mt = 0; mt < 4; ++mt)
      a[mt] = *(const bf16x8*)&s_h1[(mt * 16 + l15) * 136 + ch * 32 + quad * 8];
    #pragma unroll
    for (int nt = 0; nt < 4; ++nt)
      b[nt] = *(const bf16x8*)&w1t[(size_t)(wave * 64 + nt * 16 + l15) * 128 + ch * 32 + quad * 8];
    #pragma unroll
    for (int mt = 0; mt < 4; ++mt)
      #pragma unroll
      for (int nt = 0; nt < 4; ++nt)
        acc1[mt][nt] = __builtin_amdgcn_mfma_f32_16x16x32_bf16(a[mt], b[nt], acc1[mt][nt], 0, 0, 0);
  }
  #pragma unroll
  for (int nt = 0; nt < 4; ++nt) {
    int col = wave * 64 + nt * 16 + l15;
    float bias = b1[col];
    #pragma unroll
    for (int mt = 0; mt < 4; ++mt)
      #pragma unroll
      for (int rg = 0; rg < 4; ++rg) {
        int row = mt * 16 + quad * 4 + rg;
        s_h2[row * 264 + col] = f2bf(geluf(acc1[mt][nt][rg] + bias));
      }
  }
  __syncthreads();

  // ---------- layer 2: 256 -> 128, GELU ----------
  f32x4 acc2[4][2];
  #pragma unroll
  for (int mt = 0; mt < 4; ++mt)
    #pragma unroll
    for (int nt = 0; nt < 2; ++nt) acc2[mt][nt] = (f32x4){0.f, 0.f, 0.f, 0.f};
  for (int ch = 0; ch < 8; ++ch) {
    bf16x8 a[4], b[2];
    #pragma unroll
    for (int mt = 0; mt < 4; ++mt)
      a[mt] = *(const bf16x8*)&s_h2[(mt * 16 + l15) * 264 + ch * 32 + quad * 8];
    #pragma unroll
    for (int nt = 0; nt < 2; ++nt)
      b[nt] = *(const bf16x8*)&w2t[(size_t)(wave * 32 + nt * 16 + l15) * 256 + ch * 32 + quad * 8];
    #pragma unroll
    for (int mt = 0; mt < 4; ++mt)
      #pragma unroll
      for (int nt = 0; nt < 2; ++nt)
        acc2[mt][nt] = __builtin_amdgcn_mfma_f32_16x16x32_bf16(a[mt], b[nt], acc2[mt][nt], 0, 0, 0);
  }
  __syncthreads();   // fence: all waves done READING s_h2 before epi writes s_h1/h3 ordering below
  // write h3 into s_h1
  #pragma unroll
  for (int nt = 0; nt < 2; ++nt) {
    int col = wave * 32 + nt * 16 + l15;
    float bias = b2[col];
    #pragma unroll
    for (int mt = 0; mt < 4; ++mt)
      #pragma unroll
      for (int rg = 0; rg < 4; ++rg) {
        int row = mt * 16 + quad * 4 + rg;
        s_h1[row * 136 + col] = f2bf(geluf(acc2[mt][nt][rg] + bias));
      }
  }
  __syncthreads();

  // ---------- layer 3: 128 -> 32, linear; result -> s_kern (fp32, stride 33) ----------
  f32x4 acc3[2];
  acc3[0] = (f32x4){0.f, 0.f, 0.f, 0.f};
  acc3[1] = (f32x4){0.f, 0.f, 0.f, 0.f};
  for (int ch = 0; ch < 4; ++ch) {
    bf16x8 a3 = *(const bf16x8*)&s_h1[(wave * 16 + l15) * 136 + ch * 32 + quad * 8];
    bf16x8 b3f[2];
    #pragma unroll
    for (int nt = 0; nt < 2; ++nt)
      b3f[nt] = *(const bf16x8*)&w3t[(size_t)(nt * 16 + l15) * 128 + ch * 32 + quad * 8];
    #pragma unroll
    for (int nt = 0; nt < 2; ++nt)
      acc3[nt] = __builtin_amdgcn_mfma_f32_16x16x32_bf16(a3, b3f[nt], acc3[nt], 0, 0, 0);
  }
  #pragma unroll
  for (int nt = 0; nt < 2; ++nt) {
    int col = nt * 16 + l15;
    float bias = b3[col];
    #pragma unroll
    for (int rg = 0; rg < 4; ++rg) {
      int row = wave * 16 + quad * 4 + rg;
      s_kern[row * 33 + col] = acc3[nt][rg] + bias;   // s_h2 alias: all h2 reads fenced above
    }
  }
  __syncthreads();

  // ---------- fused reduce: out[t][x][c] = sum_j kern[x*8+j][c] * f_y[t][idx][c] ----------
  {
    const int xloc = tid >> 5;     // 0..7 local x-point
    const int c    = tid & 31;
    float acc[TDIM] = {0.f, 0.f, 0.f, 0.f};
    const int ebase = xloc * 8;
    #pragma unroll
    for (int j = 0; j < KNBR; ++j) {
      float kv = s_kern[(ebase + j) * 33 + c];
      int idx = s_idx[ebase + j];
      const float* fp = f_y + (size_t)idx * CDIM + c;
      #pragma unroll
      for (int t = 0; t < TDIM; ++t)
        acc[t] += kv * fp[(size_t)t * N_Y * CDIM];
    }
    const int xg = blockIdx.x * 8 + xloc;
    #pragma unroll
    for (int t = 0; t < TDIM; ++t)
      out[((size_t)t * N_X + xg) * CDIM + c] = acc[t];
  }
}

extern "C" void kernel_launch(void* const* d_in, const int* in_sizes, int n_in,
                              void* d_out, int out_size, void* d_ws, size_t ws_size,
                              hipStream_t stream)
{
  const float* y   = (const float*)d_in[0];
  const float* x   = (const float*)d_in[1];
  const float* f_y = (const float*)d_in[2];
  const int*  nidx = (const int*)d_in[3];
  const float* W0 = (const float*)d_in[4];  const float* b0 = (const float*)d_in[5];
  const float* W1 = (const float*)d_in[6];  const float* b1 = (const float*)d_in[7];
  const float* W2 = (const float*)d_in[8];  const float* b2 = (const float*)d_in[9];
  const float* W3 = (const float*)d_in[10]; const float* b3 = (const float*)d_in[11];

  char* ws = (char*)d_ws;
  short* yemb = (short*)(ws + 0);          // 50000*192*2 = 19,200,000
  short* xemb = (short*)(ws + 19200000);   // 32768*192*2 = 12,582,912
  short* w0t  = (short*)(ws + 31782912);   // 128*384*2  =     98,304
  short* w1t  = (short*)(ws + 31881216);   // 256*128*2  =     65,536
  short* w2t  = (short*)(ws + 31946752);   // 128*256*2  =     65,536
  short* w3t  = (short*)(ws + 32012288);   //  32*128*2  =      8,192

  hipLaunchKernelGGL(embed_all, dim3(((N_Y + N_X) * 96 + 255) / 256), dim3(256), 0, stream,
                     y, x, yemb);
  hipLaunchKernelGGL(transpose_all, dim3((118784 + 255) / 256), dim3(256), 0, stream,
                     W0, W1, W2, W3, w0t, w1t, w2t, w3t);
  hipLaunchKernelGGL(fused_mlp, dim3(ECNT / 64), dim3(256), 0, stream,
                     yemb, xemb, nidx, f_y, w0t, b0, w1t, b1, w2t, b2, w3t, b3,
                     (float*)d_out);
}